// Round 1
// baseline (140.668 us; speedup 1.0000x reference)
//
#include <hip/hip_runtime.h>
#include <cstdint>

#define D 128
#define K 1024
#define NB 4096
#define BB 8     // rows per block in main kernel
#define TK 64    // centroid rows per LDS tile
#define FEPS 1e-6f

// ---------------------------------------------------------------------------
// Kernel A: per-column extremes of centroids.
// ws layout (floats): [0:128) col min value, [128:256) col max value,
// (as ints) [256:384) first index of min, [384:512) first index of max.
// ---------------------------------------------------------------------------
__global__ __launch_bounds__(256) void col_extremes_kernel(
    const float* __restrict__ cen, float* __restrict__ ws)
{
    __shared__ float mv[256]; __shared__ int mi[256];
    __shared__ float Mv[256]; __shared__ int Mi[256];
    const int dcol = blockIdx.x;
    const int t = threadIdx.x;

    float lminv = 3.4e38f; int lmini = 0;
    float lmaxv = -3.4e38f; int lmaxi = 0;
    #pragma unroll
    for (int j = 0; j < 4; ++j) {
        int k = t * 4 + j;                 // ascending k per thread -> first-index ties ok
        float v = cen[k * D + dcol];
        if (v < lminv) { lminv = v; lmini = k; }
        if (v > lmaxv) { lmaxv = v; lmaxi = k; }
    }
    mv[t] = lminv; mi[t] = lmini; Mv[t] = lmaxv; Mi[t] = lmaxi;
    __syncthreads();
    for (int s = 128; s > 0; s >>= 1) {
        if (t < s) {
            float ov = mv[t + s]; int oi = mi[t + s];
            if (ov < mv[t] || (ov == mv[t] && oi < mi[t])) { mv[t] = ov; mi[t] = oi; }
            float Ov = Mv[t + s]; int Oi = Mi[t + s];
            if (Ov > Mv[t] || (Ov == Mv[t] && Oi < Mi[t])) { Mv[t] = Ov; Mi[t] = Oi; }
        }
        __syncthreads();
    }
    if (t == 0) {
        ws[dcol]     = mv[0];
        ws[D + dcol] = Mv[0];
        ((int*)ws)[2 * D + dcol] = mi[0];
        ((int*)ws)[3 * D + dcol] = Mi[0];
    }
}

// ---------------------------------------------------------------------------
// Main kernel: one block handles BB=8 rows of x.
//  - brute-force argmin scan over K (centroid tiles staged in LDS)
//  - argmax from precomputed column extremes
//  - per-row mode via LDS counting (reuses the 32KB tile buffer)
//  - triplet distances + atomic mean accumulation
// ---------------------------------------------------------------------------
__global__ __launch_bounds__(256) void cluster_triplet_kernel(
    const float* __restrict__ x, const float* __restrict__ cen,
    const float* __restrict__ ws, float* __restrict__ out)
{
    __shared__ float ctile[TK * D];           // 32 KB; reused as counts[BB*K] u32
    __shared__ float xs[BB * D];              // 4 KB
    __shared__ unsigned short imin[BB * D];   // 2 KB
    __shared__ unsigned short imax[BB * D];   // 2 KB
    __shared__ int modes[2 * BB];

    const int t = threadIdx.x;
    const int b0 = blockIdx.x * BB;

    // stage the 8 x-rows (1024 floats = 256 float4, coalesced)
    ((float4*)xs)[t] = ((const float4*)(x + (size_t)b0 * D))[t];
    __syncthreads();

    const int d = t & (D - 1);   // dimension owned by this thread
    const int g = t >> 7;        // row-group 0/1 (rows g*4 .. g*4+3)

    float xr[4];
    #pragma unroll
    for (int r = 0; r < 4; ++r) xr[r] = xs[(g * 4 + r) * D + d];

    float best[4]; int bidx[4];
    #pragma unroll
    for (int r = 0; r < 4; ++r) { best[r] = 3.4e38f; bidx[r] = 0; }

    for (int kt = 0; kt < K / TK; ++kt) {
        __syncthreads();   // previous tile fully consumed
        {
            // tile rows kt*TK..+TK are 32KB contiguous in global: linear copy
            const float4* src = (const float4*)(cen + (size_t)kt * TK * D);
            float4* dst = (float4*)ctile;
            #pragma unroll
            for (int j = 0; j < 8; ++j) dst[t + 256 * j] = src[t + 256 * j];
        }
        __syncthreads();
        #pragma unroll 8
        for (int kk = 0; kk < TK; ++kk) {
            float cv = ctile[kk * D + d];      // 64 consecutive floats/wave: conflict-free
            int kg = kt * TK + kk;
            #pragma unroll
            for (int r = 0; r < 4; ++r) {
                float ad = fabsf(xr[r] - cv);
                if (ad < best[r]) { best[r] = ad; bidx[r] = kg; }   // strict < -> first index
            }
        }
    }

    #pragma unroll
    for (int r = 0; r < 4; ++r) imin[(g * 4 + r) * D + d] = (unsigned short)bidx[r];

    // idx_max from column extremes, replicating reference rounding: fl((fl(x-c))^2)
    {
        float cminv = ws[d], cmaxv = ws[D + d];
        int cmini = ((const int*)ws)[2 * D + d];
        int cmaxi = ((const int*)ws)[3 * D + d];
        #pragma unroll
        for (int r = 0; r < 4; ++r) {
            float d1 = xr[r] - cminv;
            float d2 = xr[r] - cmaxv;
            float s1 = d1 * d1, s2 = d2 * d2;
            int idx;
            if (s1 > s2) idx = cmini;
            else if (s2 > s1) idx = cmaxi;
            else idx = (cmini < cmaxi) ? cmini : cmaxi;   // tie -> smaller index
            imax[(g * 4 + r) * D + d] = (unsigned short)idx;
        }
    }
    __syncthreads();

    // per-row mode via counting in the reused 32KB buffer
    unsigned int* counts = (unsigned int*)ctile;   // BB * K u32
    const int row = t >> 5;
    const int lane = t & 31;
    for (int pass = 0; pass < 2; ++pass) {
        {
            uint4* cz = (uint4*)counts;
            uint4 z = make_uint4(0u, 0u, 0u, 0u);
            #pragma unroll
            for (int j = 0; j < 8; ++j) cz[t + 256 * j] = z;
        }
        __syncthreads();
        const unsigned short* src = (pass == 0) ? imin : imax;
        #pragma unroll
        for (int r = 0; r < 4; ++r) {
            int rr = g * 4 + r;
            atomicAdd(&counts[rr * K + (int)src[rr * D + d]], 1u);
        }
        __syncthreads();
        // argmax count, tie -> smallest index; key packs both
        unsigned int bkey = 0u;
        for (int j = 0; j < 32; ++j) {
            int idx = j * 32 + lane;                    // lanes consecutive: conflict-free
            unsigned int cnt = counts[row * K + idx];
            unsigned int key = (cnt << 10) | (1023u - (unsigned)idx);
            bkey = (key > bkey) ? key : bkey;
        }
        #pragma unroll
        for (int m = 16; m >= 1; m >>= 1) {
            unsigned int o = __shfl_xor(bkey, m);
            bkey = (o > bkey) ? o : bkey;
        }
        if (lane == 0) modes[pass * BB + row] = 1023 - (int)(bkey & 1023u);
        __syncthreads();
    }

    // triplet distances: 32 lanes per row, 4 dims each
    {
        int pm = modes[0 * BB + row];
        int nm = modes[1 * BB + row];
        const float* pr = cen + (size_t)pm * D;
        const float* nr = cen + (size_t)nm * D;
        float a1 = 0.f, a2 = 0.f, a3 = 0.f;
        #pragma unroll
        for (int j = 0; j < 4; ++j) {
            int dd = j * 32 + lane;
            float xv = xs[row * D + dd];
            float pv = pr[dd], nv = nr[dd];
            float e1 = xv - pv + FEPS;
            float e2 = xv - nv + FEPS;
            float e3 = pv - nv + FEPS;
            a1 += e1 * e1; a2 += e2 * e2; a3 += e3 * e3;
        }
        #pragma unroll
        for (int m = 16; m >= 1; m >>= 1) {
            a1 += __shfl_xor(a1, m);
            a2 += __shfl_xor(a2, m);
            a3 += __shfl_xor(a3, m);
        }
        if (lane == 0) {
            float dp = sqrtf(a1);
            float dneg = fminf(sqrtf(a2), sqrtf(a3));
            float term = dp - dneg + 1.0f;
            if (term > 0.f) atomicAdd(out, term * (1.0f / NB));
        }
    }
}

extern "C" void kernel_launch(void* const* d_in, const int* in_sizes, int n_in,
                              void* d_out, int out_size, void* d_ws, size_t ws_size,
                              hipStream_t stream) {
    (void)in_sizes; (void)n_in; (void)out_size; (void)ws_size;
    const float* x   = (const float*)d_in[0];   // [4096,128] f32
    const float* cen = (const float*)d_in[1];   // [1024,128] f32
    float* out = (float*)d_out;                 // scalar f32
    float* ws  = (float*)d_ws;                  // needs 2 KB

    hipMemsetAsync(d_out, 0, sizeof(float), stream);   // out is poisoned each launch
    col_extremes_kernel<<<D, 256, 0, stream>>>(cen, ws);
    cluster_triplet_kernel<<<NB / BB, 256, 0, stream>>>(x, cen, ws, out);
}

// Round 2
// 132.097 us; speedup vs baseline: 1.0649x; 1.0649x over previous
//
#include <hip/hip_runtime.h>
#include <cstdint>

#define D 128
#define K 1024
#define NB 4096
#define BB 8     // rows per block in main kernel
#define TK 64    // centroid rows per LDS tile (fallback path)
#define FEPS 1e-6f

// ============================================================================
// ws layout (new path):
//   sval : 128 * 1024 f32  — each column of centroids sorted ascending   (512KB)
//   shead: 128 * 1024 u16  — run-head original index per sorted position (256KB)
//   ext  : [0:128) col min val, [128:256) col max val (f32);
//          as ints [256:384) first idx of min, [384:512) first idx of max (2KB)
// ============================================================================

// ---------------------------------------------------------------------------
// Kernel A: per-column bitonic sort by (value, index) + run heads + extremes.
// One block per column d. 256 threads, 1024 elements.
// ---------------------------------------------------------------------------
__global__ __launch_bounds__(256) void sort_columns_kernel(
    const float* __restrict__ cen, float* __restrict__ sval,
    unsigned short* __restrict__ shead, float* __restrict__ ext)
{
    __shared__ unsigned long long key[K];   // 8 KB
    const int dcol = blockIdx.x;
    const int t = threadIdx.x;

    #pragma unroll
    for (int j = 0; j < 4; ++j) {
        int k = t + 256 * j;
        float v = cen[k * D + dcol];
        unsigned int u = __float_as_uint(v);
        u = (u & 0x80000000u) ? ~u : (u | 0x80000000u);   // monotone map
        key[k] = ((unsigned long long)u << 32) | (unsigned int)k;
    }
    __syncthreads();

    for (int sz = 2; sz <= K; sz <<= 1) {
        for (int st = sz >> 1; st >= 1; st >>= 1) {
            #pragma unroll
            for (int j = 0; j < 4; ++j) {
                int i = t + 256 * j;
                int ixj = i ^ st;
                if (ixj > i) {
                    unsigned long long a = key[i], b = key[ixj];
                    bool up = ((i & sz) == 0);
                    bool sw = up ? (a > b) : (a < b);
                    if (sw) { key[i] = b; key[ixj] = a; }
                }
            }
            __syncthreads();
        }
    }

    #pragma unroll
    for (int j = 0; j < 4; ++j) {
        int p = t + 256 * j;
        unsigned long long kp = key[p];
        unsigned int vb = (unsigned int)(kp >> 32);
        int p0 = p;
        while (p0 > 0 && (unsigned int)(key[p0 - 1] >> 32) == vb) --p0;  // rare
        int head = (int)(key[p0] & 1023u);
        unsigned int u = (vb & 0x80000000u) ? (vb & 0x7FFFFFFFu) : ~vb; // unmap
        float v = __uint_as_float(u);
        sval[dcol * K + p] = v;
        shead[dcol * K + p] = (unsigned short)head;
        if (p == 0)     { ext[dcol]     = v; ((int*)ext)[2 * D + dcol] = head; }
        if (p == K - 1) { ext[D + dcol] = v; ((int*)ext)[3 * D + dcol] = head; }
    }
}

// ---------------------------------------------------------------------------
// Main kernel (new path): binary-search argmin + extremes argmax + mode + loss
// ---------------------------------------------------------------------------
__global__ __launch_bounds__(256) void cluster_triplet_bs_kernel(
    const float* __restrict__ x, const float* __restrict__ cen,
    const float* __restrict__ sval, const unsigned short* __restrict__ shead,
    const float* __restrict__ ext, float* __restrict__ out)
{
    __shared__ unsigned int counts[BB * K];   // 32 KB
    __shared__ float xs[BB * D];              // 4 KB
    __shared__ unsigned short imin[BB * D];   // 2 KB
    __shared__ unsigned short imax[BB * D];   // 2 KB
    __shared__ int modes[2 * BB];

    const int t = threadIdx.x;
    const int b0 = blockIdx.x * BB;

    ((float4*)xs)[t] = ((const float4*)(x + (size_t)b0 * D))[t];
    __syncthreads();

    const int d = t & (D - 1);
    const int g = t >> 7;

    float xr[4];
    #pragma unroll
    for (int r = 0; r < 4; ++r) xr[r] = xs[(g * 4 + r) * D + d];

    // ---- branchless binary search: pos = last index with sval <= x ----
    const float* vs = sval + d * K;
    int pos[4];
    #pragma unroll
    for (int r = 0; r < 4; ++r) pos[r] = -1;
    #pragma unroll
    for (int s = K; s >= 1; s >>= 1) {
        #pragma unroll
        for (int r = 0; r < 4; ++r) {
            int cand = pos[r] + s;
            int cc = cand > K - 1 ? K - 1 : cand;
            float v = vs[cc];
            if (cand <= K - 1 && v <= xr[r]) pos[r] = cand;
        }
    }
    #pragma unroll
    for (int r = 0; r < 4; ++r) {
        int p1 = pos[r], p2 = pos[r] + 1;
        int c1 = p1 < 0 ? 0 : p1;
        int c2 = p2 > K - 1 ? K - 1 : p2;
        float v1 = vs[c1], v2 = vs[c2];
        int h1 = shead[d * K + c1], h2 = shead[d * K + c2];
        float d1 = xr[r] - v1, d2 = xr[r] - v2;
        float s1 = d1 * d1, s2 = d2 * d2;
        if (p1 < 0) s1 = 3.4e38f;
        if (p2 > K - 1) s2 = 3.4e38f;
        int idx;
        if (s1 < s2) idx = h1;
        else if (s2 < s1) idx = h2;
        else idx = h1 < h2 ? h1 : h2;       // sq tie -> smaller original index
        imin[(g * 4 + r) * D + d] = (unsigned short)idx;
    }

    // ---- idx_max from column extremes (reference rounding) ----
    {
        float cminv = ext[d], cmaxv = ext[D + d];
        int cmini = ((const int*)ext)[2 * D + d];
        int cmaxi = ((const int*)ext)[3 * D + d];
        #pragma unroll
        for (int r = 0; r < 4; ++r) {
            float d1 = xr[r] - cminv;
            float d2 = xr[r] - cmaxv;
            float s1 = d1 * d1, s2 = d2 * d2;
            int idx;
            if (s1 > s2) idx = cmini;
            else if (s2 > s1) idx = cmaxi;
            else idx = (cmini < cmaxi) ? cmini : cmaxi;
            imax[(g * 4 + r) * D + d] = (unsigned short)idx;
        }
    }
    __syncthreads();

    // ---- per-row mode via LDS counting ----
    const int row = t >> 5;
    const int lane = t & 31;
    for (int pass = 0; pass < 2; ++pass) {
        {
            uint4* cz = (uint4*)counts;
            uint4 z = make_uint4(0u, 0u, 0u, 0u);
            #pragma unroll
            for (int j = 0; j < 8; ++j) cz[t + 256 * j] = z;
        }
        __syncthreads();
        const unsigned short* src = (pass == 0) ? imin : imax;
        #pragma unroll
        for (int r = 0; r < 4; ++r) {
            int rr = g * 4 + r;
            atomicAdd(&counts[rr * K + (int)src[rr * D + d]], 1u);
        }
        __syncthreads();
        unsigned int bkey = 0u;
        for (int j = 0; j < 32; ++j) {
            int idx = j * 32 + lane;
            unsigned int cnt = counts[row * K + idx];
            unsigned int key = (cnt << 10) | (1023u - (unsigned)idx);
            bkey = (key > bkey) ? key : bkey;
        }
        #pragma unroll
        for (int m = 16; m >= 1; m >>= 1) {
            unsigned int o = __shfl_xor(bkey, m);
            bkey = (o > bkey) ? o : bkey;
        }
        if (lane == 0) modes[pass * BB + row] = 1023 - (int)(bkey & 1023u);
        __syncthreads();
    }

    // ---- triplet distances ----
    {
        int pm = modes[0 * BB + row];
        int nm = modes[1 * BB + row];
        const float* pr = cen + (size_t)pm * D;
        const float* nr = cen + (size_t)nm * D;
        float a1 = 0.f, a2 = 0.f, a3 = 0.f;
        #pragma unroll
        for (int j = 0; j < 4; ++j) {
            int dd = j * 32 + lane;
            float xv = xs[row * D + dd];
            float pv = pr[dd], nv = nr[dd];
            float e1 = xv - pv + FEPS;
            float e2 = xv - nv + FEPS;
            float e3 = pv - nv + FEPS;
            a1 += e1 * e1; a2 += e2 * e2; a3 += e3 * e3;
        }
        #pragma unroll
        for (int m = 16; m >= 1; m >>= 1) {
            a1 += __shfl_xor(a1, m);
            a2 += __shfl_xor(a2, m);
            a3 += __shfl_xor(a3, m);
        }
        if (lane == 0) {
            float dp = sqrtf(a1);
            float dneg = fminf(sqrtf(a2), sqrtf(a3));
            float term = dp - dneg + 1.0f;
            if (term > 0.f) atomicAdd(out, term * (1.0f / NB));
        }
    }
}

// ===========================================================================
// Fallback path (verified round-1 kernels) for small ws_size
// ===========================================================================
__global__ __launch_bounds__(256) void col_extremes_kernel(
    const float* __restrict__ cen, float* __restrict__ ws)
{
    __shared__ float mv[256]; __shared__ int mi[256];
    __shared__ float Mv[256]; __shared__ int Mi[256];
    const int dcol = blockIdx.x;
    const int t = threadIdx.x;

    float lminv = 3.4e38f; int lmini = 0;
    float lmaxv = -3.4e38f; int lmaxi = 0;
    #pragma unroll
    for (int j = 0; j < 4; ++j) {
        int k = t * 4 + j;
        float v = cen[k * D + dcol];
        if (v < lminv) { lminv = v; lmini = k; }
        if (v > lmaxv) { lmaxv = v; lmaxi = k; }
    }
    mv[t] = lminv; mi[t] = lmini; Mv[t] = lmaxv; Mi[t] = lmaxi;
    __syncthreads();
    for (int s = 128; s > 0; s >>= 1) {
        if (t < s) {
            float ov = mv[t + s]; int oi = mi[t + s];
            if (ov < mv[t] || (ov == mv[t] && oi < mi[t])) { mv[t] = ov; mi[t] = oi; }
            float Ov = Mv[t + s]; int Oi = Mi[t + s];
            if (Ov > Mv[t] || (Ov == Mv[t] && Oi < Mi[t])) { Mv[t] = Ov; Mi[t] = Oi; }
        }
        __syncthreads();
    }
    if (t == 0) {
        ws[dcol]     = mv[0];
        ws[D + dcol] = Mv[0];
        ((int*)ws)[2 * D + dcol] = mi[0];
        ((int*)ws)[3 * D + dcol] = Mi[0];
    }
}

__global__ __launch_bounds__(256) void cluster_triplet_kernel(
    const float* __restrict__ x, const float* __restrict__ cen,
    const float* __restrict__ ws, float* __restrict__ out)
{
    __shared__ float ctile[TK * D];
    __shared__ float xs[BB * D];
    __shared__ unsigned short imin[BB * D];
    __shared__ unsigned short imax[BB * D];
    __shared__ int modes[2 * BB];

    const int t = threadIdx.x;
    const int b0 = blockIdx.x * BB;

    ((float4*)xs)[t] = ((const float4*)(x + (size_t)b0 * D))[t];
    __syncthreads();

    const int d = t & (D - 1);
    const int g = t >> 7;

    float xr[4];
    #pragma unroll
    for (int r = 0; r < 4; ++r) xr[r] = xs[(g * 4 + r) * D + d];

    float best[4]; int bidx[4];
    #pragma unroll
    for (int r = 0; r < 4; ++r) { best[r] = 3.4e38f; bidx[r] = 0; }

    for (int kt = 0; kt < K / TK; ++kt) {
        __syncthreads();
        {
            const float4* src = (const float4*)(cen + (size_t)kt * TK * D);
            float4* dst = (float4*)ctile;
            #pragma unroll
            for (int j = 0; j < 8; ++j) dst[t + 256 * j] = src[t + 256 * j];
        }
        __syncthreads();
        #pragma unroll 8
        for (int kk = 0; kk < TK; ++kk) {
            float cv = ctile[kk * D + d];
            int kg = kt * TK + kk;
            #pragma unroll
            for (int r = 0; r < 4; ++r) {
                float ad = fabsf(xr[r] - cv);
                if (ad < best[r]) { best[r] = ad; bidx[r] = kg; }
            }
        }
    }

    #pragma unroll
    for (int r = 0; r < 4; ++r) imin[(g * 4 + r) * D + d] = (unsigned short)bidx[r];

    {
        float cminv = ws[d], cmaxv = ws[D + d];
        int cmini = ((const int*)ws)[2 * D + d];
        int cmaxi = ((const int*)ws)[3 * D + d];
        #pragma unroll
        for (int r = 0; r < 4; ++r) {
            float d1 = xr[r] - cminv;
            float d2 = xr[r] - cmaxv;
            float s1 = d1 * d1, s2 = d2 * d2;
            int idx;
            if (s1 > s2) idx = cmini;
            else if (s2 > s1) idx = cmaxi;
            else idx = (cmini < cmaxi) ? cmini : cmaxi;
            imax[(g * 4 + r) * D + d] = (unsigned short)idx;
        }
    }
    __syncthreads();

    unsigned int* counts = (unsigned int*)ctile;
    const int row = t >> 5;
    const int lane = t & 31;
    for (int pass = 0; pass < 2; ++pass) {
        {
            uint4* cz = (uint4*)counts;
            uint4 z = make_uint4(0u, 0u, 0u, 0u);
            #pragma unroll
            for (int j = 0; j < 8; ++j) cz[t + 256 * j] = z;
        }
        __syncthreads();
        const unsigned short* src = (pass == 0) ? imin : imax;
        #pragma unroll
        for (int r = 0; r < 4; ++r) {
            int rr = g * 4 + r;
            atomicAdd(&counts[rr * K + (int)src[rr * D + d]], 1u);
        }
        __syncthreads();
        unsigned int bkey = 0u;
        for (int j = 0; j < 32; ++j) {
            int idx = j * 32 + lane;
            unsigned int cnt = counts[row * K + idx];
            unsigned int key = (cnt << 10) | (1023u - (unsigned)idx);
            bkey = (key > bkey) ? key : bkey;
        }
        #pragma unroll
        for (int m = 16; m >= 1; m >>= 1) {
            unsigned int o = __shfl_xor(bkey, m);
            bkey = (o > bkey) ? o : bkey;
        }
        if (lane == 0) modes[pass * BB + row] = 1023 - (int)(bkey & 1023u);
        __syncthreads();
    }

    {
        int pm = modes[0 * BB + row];
        int nm = modes[1 * BB + row];
        const float* pr = cen + (size_t)pm * D;
        const float* nr = cen + (size_t)nm * D;
        float a1 = 0.f, a2 = 0.f, a3 = 0.f;
        #pragma unroll
        for (int j = 0; j < 4; ++j) {
            int dd = j * 32 + lane;
            float xv = xs[row * D + dd];
            float pv = pr[dd], nv = nr[dd];
            float e1 = xv - pv + FEPS;
            float e2 = xv - nv + FEPS;
            float e3 = pv - nv + FEPS;
            a1 += e1 * e1; a2 += e2 * e2; a3 += e3 * e3;
        }
        #pragma unroll
        for (int m = 16; m >= 1; m >>= 1) {
            a1 += __shfl_xor(a1, m);
            a2 += __shfl_xor(a2, m);
            a3 += __shfl_xor(a3, m);
        }
        if (lane == 0) {
            float dp = sqrtf(a1);
            float dneg = fminf(sqrtf(a2), sqrtf(a3));
            float term = dp - dneg + 1.0f;
            if (term > 0.f) atomicAdd(out, term * (1.0f / NB));
        }
    }
}

extern "C" void kernel_launch(void* const* d_in, const int* in_sizes, int n_in,
                              void* d_out, int out_size, void* d_ws, size_t ws_size,
                              hipStream_t stream) {
    (void)in_sizes; (void)n_in; (void)out_size;
    const float* x   = (const float*)d_in[0];   // [4096,128] f32
    const float* cen = (const float*)d_in[1];   // [1024,128] f32
    float* out = (float*)d_out;                 // scalar f32

    hipMemsetAsync(d_out, 0, sizeof(float), stream);

    const size_t need = (size_t)D * K * 4 + (size_t)D * K * 2 + 4 * D * 4;
    if (ws_size >= need) {
        float* sval = (float*)d_ws;                                // 512 KB
        unsigned short* shead = (unsigned short*)(sval + D * K);   // 256 KB
        float* ext = (float*)(shead + D * K);                      // 2 KB
        sort_columns_kernel<<<D, 256, 0, stream>>>(cen, sval, shead, ext);
        cluster_triplet_bs_kernel<<<NB / BB, 256, 0, stream>>>(x, cen, sval, shead, ext, out);
    } else {
        float* ws = (float*)d_ws;
        col_extremes_kernel<<<D, 256, 0, stream>>>(cen, ws);
        cluster_triplet_kernel<<<NB / BB, 256, 0, stream>>>(x, cen, ws, out);
    }
}

// Round 4
// 124.212 us; speedup vs baseline: 1.1325x; 1.0635x over previous
//
#include <hip/hip_runtime.h>
#include <cstdint>

#define D 128
#define K 1024
#define NB 4096
#define BB 8     // rows per block in main kernel
#define TK 64    // centroid rows per LDS tile (fallback path)
#define FEPS 1e-6f

typedef unsigned long long u64;

// ============================================================================
// ws layout (fast path):
//   sval : [D][K] f32   — each column of centroids sorted ascending   (512KB)
//   shead: [D][K] u16   — run-head original index per sorted position (256KB)
//   ssamp: [64][D] f32  — transposed sample table, ssamp[s][d]=sval[d][16s] (32KB)
//   ext  : [0:128) col min val, [128:256) col max val (f32);
//          as ints [256:384) first idx of min, [384:512) first idx of max (2KB)
// ============================================================================

// ---------------------------------------------------------------------------
// Register/shfl bitonic stages. Element i = j*64 + lane, key = (mappedval<<32)|idx.
// ---------------------------------------------------------------------------
template<int SZ, int ST>   // ST in {1..32}: cross-lane via shfl
__device__ __forceinline__ void bstage_lane(u64 (&key)[16], int lane) {
    #pragma unroll
    for (int j = 0; j < 16; ++j) {
        u64 a = key[j];
        u64 b = __shfl_xor(a, ST, 64);
        int i = j * 64 + lane;
        bool keepMin = (((lane & ST) == 0) == ((i & SZ) == 0));
        u64 mn = a < b ? a : b;
        u64 mx = a ^ b ^ mn;
        key[j] = keepMin ? mn : mx;
    }
}
template<int SZ, int JB>   // stride = JB*64: register-pair exchange
__device__ __forceinline__ void bstage_reg(u64 (&key)[16]) {
    #pragma unroll
    for (int j = 0; j < 16; ++j) {
        if ((j & JB) == 0) {
            const int p = j | JB;
            u64 a = key[j], b = key[p];
            bool up = (((j * 64) & SZ) == 0);
            u64 mn = a < b ? a : b;
            u64 mx = a ^ b ^ mn;
            key[j] = up ? mn : mx;
            key[p] = up ? mx : mn;
        }
    }
}
template<int SZ>
__device__ __forceinline__ void bstage_lane_tail(u64 (&key)[16], int lane) {
    bstage_lane<SZ, 32>(key, lane);
    bstage_lane<SZ, 16>(key, lane);
    bstage_lane<SZ, 8>(key, lane);
    bstage_lane<SZ, 4>(key, lane);
    bstage_lane<SZ, 2>(key, lane);
    bstage_lane<SZ, 1>(key, lane);
}

// ---------------------------------------------------------------------------
// Kernel A: per-column sort (value,idx), run heads, samples, extremes.
// One block = one wave = one column. No barriers in the sort network.
// ---------------------------------------------------------------------------
__global__ __launch_bounds__(64) void sort_columns_kernel(
    const float* __restrict__ cen, float* __restrict__ sval,
    unsigned short* __restrict__ shead, float* __restrict__ ssamp,
    float* __restrict__ ext, float* __restrict__ out)
{
    __shared__ u64 key64[K];   // 8 KB, used only for the run-head pass
    const int dcol = blockIdx.x;
    const int lane = threadIdx.x;

    if (dcol == 0 && lane == 0) out[0] = 0.0f;   // replaces memset dispatch

    u64 key[16];
    #pragma unroll
    for (int j = 0; j < 16; ++j) {
        int k = j * 64 + lane;
        float v = cen[k * D + dcol];
        unsigned int u = __float_as_uint(v);
        u = (u & 0x80000000u) ? ~u : (u | 0x80000000u);   // monotone map
        key[j] = ((u64)u << 32) | (unsigned int)k;
    }

    // bitonic network: 55 stages, all in registers / shfl
    bstage_lane<2, 1>(key, lane);
    bstage_lane<4, 2>(key, lane);  bstage_lane<4, 1>(key, lane);
    bstage_lane<8, 4>(key, lane);  bstage_lane<8, 2>(key, lane);  bstage_lane<8, 1>(key, lane);
    bstage_lane<16, 8>(key, lane); bstage_lane<16, 4>(key, lane);
    bstage_lane<16, 2>(key, lane); bstage_lane<16, 1>(key, lane);
    bstage_lane<32, 16>(key, lane); bstage_lane<32, 8>(key, lane);
    bstage_lane<32, 4>(key, lane);  bstage_lane<32, 2>(key, lane);
    bstage_lane<32, 1>(key, lane);
    bstage_lane_tail<64>(key, lane);
    bstage_reg<128, 1>(key);  bstage_lane_tail<128>(key, lane);
    bstage_reg<256, 2>(key);  bstage_reg<256, 1>(key);  bstage_lane_tail<256>(key, lane);
    bstage_reg<512, 4>(key);  bstage_reg<512, 2>(key);  bstage_reg<512, 1>(key);
    bstage_lane_tail<512>(key, lane);
    bstage_reg<1024, 8>(key); bstage_reg<1024, 4>(key); bstage_reg<1024, 2>(key);
    bstage_reg<1024, 1>(key); bstage_lane_tail<1024>(key, lane);

    #pragma unroll
    for (int j = 0; j < 16; ++j) key64[j * 64 + lane] = key[j];
    __syncthreads();

    #pragma unroll
    for (int j = 0; j < 16; ++j) {
        int p = j * 64 + lane;
        u64 kp = key[j];
        unsigned int vb = (unsigned int)(kp >> 32);
        int p0 = p;
        while (p0 > 0 && (unsigned int)(key64[p0 - 1] >> 32) == vb) --p0;  // rare
        int head = (int)(key64[p0] & 1023u);
        unsigned int u = (vb & 0x80000000u) ? (vb & 0x7FFFFFFFu) : ~vb;    // unmap
        float v = __uint_as_float(u);
        sval[dcol * K + p] = v;
        shead[dcol * K + p] = (unsigned short)head;
        if ((p & 15) == 0) ssamp[(p >> 4) * D + dcol] = v;   // transposed
        if (p == 0)     { ext[dcol]     = v; ((int*)ext)[2 * D + dcol] = head; }
        if (p == K - 1) { ext[D + dcol] = v; ((int*)ext)[3 * D + dcol] = head; }
    }
}

// ---------------------------------------------------------------------------
// Main kernel: 3-level search (reg coarse -> LDS fine -> one global batch),
// extremes argmax, LDS-count mode, triplet loss.
// ---------------------------------------------------------------------------
__global__ __launch_bounds__(256) void cluster_triplet_bs2_kernel(
    const float* __restrict__ x, const float* __restrict__ cen,
    const float* __restrict__ sval, const unsigned short* __restrict__ shead,
    const float* __restrict__ ssamp, const float* __restrict__ ext,
    float* __restrict__ out)
{
    __shared__ unsigned int sh_mem[BB * K];   // 32 KB: samp (phase 1) ∪ counts (phase 2)
    __shared__ float xs[BB * D];              // 4 KB
    __shared__ unsigned short imin[BB * D];   // 2 KB
    __shared__ unsigned short imax[BB * D];   // 2 KB
    __shared__ int modes[2 * BB];
    float* samp = (float*)sh_mem;             // [64][D] transposed sample table

    const int t = threadIdx.x;
    const int b0 = blockIdx.x * BB;

    ((float4*)xs)[t] = ((const float4*)(x + (size_t)b0 * D))[t];
    {   // stage the 32KB sample table (8192 floats, coalesced)
        const float4* src = (const float4*)ssamp;
        float4* dst = (float4*)samp;
        #pragma unroll
        for (int j = 0; j < 8; ++j) dst[t + 256 * j] = src[t + 256 * j];
    }
    __syncthreads();

    const int d = t & (D - 1);
    const int g = t >> 7;

    float xr[4];
    #pragma unroll
    for (int r = 0; r < 4; ++r) xr[r] = xs[(g * 4 + r) * D + d];

    // level 0: 8 coarse samples (every 128th sorted value), conflict-free LDS
    float c8[8];
    #pragma unroll
    for (int m = 0; m < 8; ++m) c8[m] = samp[(m * 8) * D + d];

    // level 1: per chain, 8 fine samples -> ss = last s in [0,64) with samp[s]<=x
    int ss[4];
    #pragma unroll
    for (int r = 0; r < 4; ++r) {
        int cnt8 = 0;
        #pragma unroll
        for (int m = 0; m < 8; ++m) cnt8 += (c8[m] <= xr[r]) ? 1 : 0;
        int cb = cnt8 > 0 ? cnt8 - 1 : 0;
        int cf = 0;
        #pragma unroll
        for (int i = 1; i < 8; ++i) cf += (samp[(cb * 8 + i) * D + d] <= xr[r]) ? 1 : 0;
        ss[r] = (cnt8 == 0) ? -1 : cb * 8 + cf;
    }

    // level 2: one batched global load per chain (16 vals + 16 heads + 1 extra head)
    int q0[4];
    float4 v4[4][4];
    uint4  h4[4][2];
    unsigned int he[4];
    #pragma unroll
    for (int r = 0; r < 4; ++r) {
        q0[r] = (ss[r] < 0 ? 0 : ss[r]) * 16;
        const int base = d * K + q0[r];
        const float4* vp = (const float4*)(sval + base);
        v4[r][0] = vp[0]; v4[r][1] = vp[1]; v4[r][2] = vp[2]; v4[r][3] = vp[3];
        const uint4* hp = (const uint4*)(shead + base);
        h4[r][0] = hp[0]; h4[r][1] = hp[1];
        int qe = q0[r] + 16; if (qe > K - 1) qe = K - 1;
        he[r] = shead[d * K + qe];
    }

    #pragma unroll
    for (int r = 0; r < 4; ++r) {
        const float xv = xr[r];
        float vals[16];
        vals[0]=v4[r][0].x; vals[1]=v4[r][0].y; vals[2]=v4[r][0].z; vals[3]=v4[r][0].w;
        vals[4]=v4[r][1].x; vals[5]=v4[r][1].y; vals[6]=v4[r][1].z; vals[7]=v4[r][1].w;
        vals[8]=v4[r][2].x; vals[9]=v4[r][2].y; vals[10]=v4[r][2].z; vals[11]=v4[r][2].w;
        vals[12]=v4[r][3].x; vals[13]=v4[r][3].y; vals[14]=v4[r][3].z; vals[15]=v4[r][3].w;
        unsigned int hu[8];
        hu[0]=h4[r][0].x; hu[1]=h4[r][0].y; hu[2]=h4[r][0].z; hu[3]=h4[r][0].w;
        hu[4]=h4[r][1].x; hu[5]=h4[r][1].y; hu[6]=h4[r][1].z; hu[7]=h4[r][1].w;
        int hds[16];
        #pragma unroll
        for (int i = 0; i < 16; ++i) hds[i] = (int)((hu[i >> 1] >> ((i & 1) * 16)) & 0xFFFFu);

        float v1 = 0.f, v2 = 0.f; int h1 = 0, h2 = 0; bool has1 = false, has2 = false;
        #pragma unroll
        for (int i = 0; i < 16; ++i) {          // last val <= x (ascending)
            bool c = vals[i] <= xv;
            v1 = c ? vals[i] : v1; h1 = c ? hds[i] : h1; has1 = has1 || c;
        }
        #pragma unroll
        for (int i = 15; i >= 0; --i) {         // first val > x
            bool c = vals[i] > xv;
            v2 = c ? vals[i] : v2; h2 = c ? hds[i] : h2; has2 = has2 || c;
        }
        if (!has2) {                             // ran off the 16-run: successor = next sample
            v2 = (ss[r] < 63) ? samp[(ss[r] + 1) * D + d] : 0.f;
            h2 = (int)he[r];
            has2 = (ss[r] < 63);
        }
        float d1 = xv - v1, d2 = xv - v2;
        float s1 = has1 ? d1 * d1 : 3.4e38f;
        float s2 = has2 ? d2 * d2 : 3.4e38f;
        int idx;
        if (s1 < s2) idx = h1;
        else if (s2 < s1) idx = h2;
        else idx = h1 < h2 ? h1 : h2;            // sq tie -> smaller original index
        imin[(g * 4 + r) * D + d] = (unsigned short)idx;
    }

    // idx_max from column extremes (reference rounding)
    {
        float cminv = ext[d], cmaxv = ext[D + d];
        int cmini = ((const int*)ext)[2 * D + d];
        int cmaxi = ((const int*)ext)[3 * D + d];
        #pragma unroll
        for (int r = 0; r < 4; ++r) {
            float d1 = xr[r] - cminv;
            float d2 = xr[r] - cmaxv;
            float s1 = d1 * d1, s2 = d2 * d2;
            int idx;
            if (s1 > s2) idx = cmini;
            else if (s2 > s1) idx = cmaxi;
            else idx = (cmini < cmaxi) ? cmini : cmaxi;
            imax[(g * 4 + r) * D + d] = (unsigned short)idx;
        }
    }
    __syncthreads();

    // per-row mode via LDS counting (counts aliases samp; samp no longer needed)
    unsigned int* counts = sh_mem;
    const int row = t >> 5;
    const int lane = t & 31;
    for (int pass = 0; pass < 2; ++pass) {
        {
            uint4* cz = (uint4*)counts;
            uint4 z = make_uint4(0u, 0u, 0u, 0u);
            #pragma unroll
            for (int j = 0; j < 8; ++j) cz[t + 256 * j] = z;
        }
        __syncthreads();
        const unsigned short* src = (pass == 0) ? imin : imax;
        #pragma unroll
        for (int r = 0; r < 4; ++r) {
            int rr = g * 4 + r;
            atomicAdd(&counts[rr * K + (int)src[rr * D + d]], 1u);
        }
        __syncthreads();
        unsigned int bkey = 0u;
        for (int j = 0; j < 32; ++j) {
            int idx = j * 32 + lane;
            unsigned int cnt = counts[row * K + idx];
            unsigned int key = (cnt << 10) | (1023u - (unsigned)idx);
            bkey = (key > bkey) ? key : bkey;
        }
        #pragma unroll
        for (int m = 16; m >= 1; m >>= 1) {
            unsigned int o = __shfl_xor(bkey, m);
            bkey = (o > bkey) ? o : bkey;
        }
        if (lane == 0) modes[pass * BB + row] = 1023 - (int)(bkey & 1023u);
        __syncthreads();
    }

    // triplet distances: 32 lanes per row, 4 dims each
    {
        int pm = modes[0 * BB + row];
        int nm = modes[1 * BB + row];
        const float* pr = cen + (size_t)pm * D;
        const float* nr = cen + (size_t)nm * D;
        float a1 = 0.f, a2 = 0.f, a3 = 0.f;
        #pragma unroll
        for (int j = 0; j < 4; ++j) {
            int dd = j * 32 + lane;
            float xv = xs[row * D + dd];
            float pv = pr[dd], nv = nr[dd];
            float e1 = xv - pv + FEPS;
            float e2 = xv - nv + FEPS;
            float e3 = pv - nv + FEPS;
            a1 += e1 * e1; a2 += e2 * e2; a3 += e3 * e3;
        }
        #pragma unroll
        for (int m = 16; m >= 1; m >>= 1) {
            a1 += __shfl_xor(a1, m);
            a2 += __shfl_xor(a2, m);
            a3 += __shfl_xor(a3, m);
        }
        if (lane == 0) {
            float dp = sqrtf(a1);
            float dneg = fminf(sqrtf(a2), sqrtf(a3));
            float term = dp - dneg + 1.0f;
            if (term > 0.f) atomicAdd(out, term * (1.0f / NB));
        }
    }
}

// ===========================================================================
// Fallback path (verified round-1 kernels) for small ws_size
// ===========================================================================
__global__ __launch_bounds__(256) void col_extremes_kernel(
    const float* __restrict__ cen, float* __restrict__ ws)
{
    __shared__ float mv[256]; __shared__ int mi[256];
    __shared__ float Mv[256]; __shared__ int Mi[256];
    const int dcol = blockIdx.x;
    const int t = threadIdx.x;

    float lminv = 3.4e38f; int lmini = 0;
    float lmaxv = -3.4e38f; int lmaxi = 0;
    #pragma unroll
    for (int j = 0; j < 4; ++j) {
        int k = t * 4 + j;
        float v = cen[k * D + dcol];
        if (v < lminv) { lminv = v; lmini = k; }
        if (v > lmaxv) { lmaxv = v; lmaxi = k; }
    }
    mv[t] = lminv; mi[t] = lmini; Mv[t] = lmaxv; Mi[t] = lmaxi;
    __syncthreads();
    for (int s = 128; s > 0; s >>= 1) {
        if (t < s) {
            float ov = mv[t + s]; int oi = mi[t + s];
            if (ov < mv[t] || (ov == mv[t] && oi < mi[t])) { mv[t] = ov; mi[t] = oi; }
            float Ov = Mv[t + s]; int Oi = Mi[t + s];
            if (Ov > Mv[t] || (Ov == Mv[t] && Oi < Mi[t])) { Mv[t] = Ov; Mi[t] = Oi; }
        }
        __syncthreads();
    }
    if (t == 0) {
        ws[dcol]     = mv[0];
        ws[D + dcol] = Mv[0];
        ((int*)ws)[2 * D + dcol] = mi[0];
        ((int*)ws)[3 * D + dcol] = Mi[0];
    }
}

__global__ __launch_bounds__(256) void cluster_triplet_kernel(
    const float* __restrict__ x, const float* __restrict__ cen,
    const float* __restrict__ ws, float* __restrict__ out)
{
    __shared__ float ctile[TK * D];
    __shared__ float xs[BB * D];
    __shared__ unsigned short imin[BB * D];
    __shared__ unsigned short imax[BB * D];
    __shared__ int modes[2 * BB];

    const int t = threadIdx.x;
    const int b0 = blockIdx.x * BB;

    ((float4*)xs)[t] = ((const float4*)(x + (size_t)b0 * D))[t];
    __syncthreads();

    const int d = t & (D - 1);
    const int g = t >> 7;

    float xr[4];
    #pragma unroll
    for (int r = 0; r < 4; ++r) xr[r] = xs[(g * 4 + r) * D + d];

    float best[4]; int bidx[4];
    #pragma unroll
    for (int r = 0; r < 4; ++r) { best[r] = 3.4e38f; bidx[r] = 0; }

    for (int kt = 0; kt < K / TK; ++kt) {
        __syncthreads();
        {
            const float4* src = (const float4*)(cen + (size_t)kt * TK * D);
            float4* dst = (float4*)ctile;
            #pragma unroll
            for (int j = 0; j < 8; ++j) dst[t + 256 * j] = src[t + 256 * j];
        }
        __syncthreads();
        #pragma unroll 8
        for (int kk = 0; kk < TK; ++kk) {
            float cv = ctile[kk * D + d];
            int kg = kt * TK + kk;
            #pragma unroll
            for (int r = 0; r < 4; ++r) {
                float ad = fabsf(xr[r] - cv);
                if (ad < best[r]) { best[r] = ad; bidx[r] = kg; }
            }
        }
    }

    #pragma unroll
    for (int r = 0; r < 4; ++r) imin[(g * 4 + r) * D + d] = (unsigned short)bidx[r];

    {
        float cminv = ws[d], cmaxv = ws[D + d];
        int cmini = ((const int*)ws)[2 * D + d];
        int cmaxi = ((const int*)ws)[3 * D + d];
        #pragma unroll
        for (int r = 0; r < 4; ++r) {
            float d1 = xr[r] - cminv;
            float d2 = xr[r] - cmaxv;
            float s1 = d1 * d1, s2 = d2 * d2;
            int idx;
            if (s1 > s2) idx = cmini;
            else if (s2 > s1) idx = cmaxi;
            else idx = (cmini < cmaxi) ? cmini : cmaxi;
            imax[(g * 4 + r) * D + d] = (unsigned short)idx;
        }
    }
    __syncthreads();

    unsigned int* counts = (unsigned int*)ctile;
    const int row = t >> 5;
    const int lane = t & 31;
    for (int pass = 0; pass < 2; ++pass) {
        {
            uint4* cz = (uint4*)counts;
            uint4 z = make_uint4(0u, 0u, 0u, 0u);
            #pragma unroll
            for (int j = 0; j < 8; ++j) cz[t + 256 * j] = z;
        }
        __syncthreads();
        const unsigned short* src = (pass == 0) ? imin : imax;
        #pragma unroll
        for (int r = 0; r < 4; ++r) {
            int rr = g * 4 + r;
            atomicAdd(&counts[rr * K + (int)src[rr * D + d]], 1u);
        }
        __syncthreads();
        unsigned int bkey = 0u;
        for (int j = 0; j < 32; ++j) {
            int idx = j * 32 + lane;
            unsigned int cnt = counts[row * K + idx];
            unsigned int key = (cnt << 10) | (1023u - (unsigned)idx);
            bkey = (key > bkey) ? key : bkey;
        }
        #pragma unroll
        for (int m = 16; m >= 1; m >>= 1) {
            unsigned int o = __shfl_xor(bkey, m);
            bkey = (o > bkey) ? o : bkey;
        }
        if (lane == 0) modes[pass * BB + row] = 1023 - (int)(bkey & 1023u);
        __syncthreads();
    }

    {
        int pm = modes[0 * BB + row];
        int nm = modes[1 * BB + row];
        const float* pr = cen + (size_t)pm * D;
        const float* nr = cen + (size_t)nm * D;
        float a1 = 0.f, a2 = 0.f, a3 = 0.f;
        #pragma unroll
        for (int j = 0; j < 4; ++j) {
            int dd = j * 32 + lane;
            float xv = xs[row * D + dd];
            float pv = pr[dd], nv = nr[dd];
            float e1 = xv - pv + FEPS;
            float e2 = xv - nv + FEPS;
            float e3 = pv - nv + FEPS;
            a1 += e1 * e1; a2 += e2 * e2; a3 += e3 * e3;
        }
        #pragma unroll
        for (int m = 16; m >= 1; m >>= 1) {
            a1 += __shfl_xor(a1, m);
            a2 += __shfl_xor(a2, m);
            a3 += __shfl_xor(a3, m);
        }
        if (lane == 0) {
            float dp = sqrtf(a1);
            float dneg = fminf(sqrtf(a2), sqrtf(a3));
            float term = dp - dneg + 1.0f;
            if (term > 0.f) atomicAdd(out, term * (1.0f / NB));
        }
    }
}

extern "C" void kernel_launch(void* const* d_in, const int* in_sizes, int n_in,
                              void* d_out, int out_size, void* d_ws, size_t ws_size,
                              hipStream_t stream) {
    (void)in_sizes; (void)n_in; (void)out_size;
    const float* x   = (const float*)d_in[0];   // [4096,128] f32
    const float* cen = (const float*)d_in[1];   // [1024,128] f32
    float* out = (float*)d_out;                 // scalar f32

    const size_t need = (size_t)D * K * 4 + (size_t)D * K * 2
                      + (size_t)64 * D * 4 + (size_t)4 * D * 4;
    if (ws_size >= need) {
        float* sval = (float*)d_ws;                                 // 512 KB
        unsigned short* shead = (unsigned short*)(sval + D * K);    // 256 KB
        float* ssamp = (float*)(shead + D * K);                     // 32 KB
        float* ext = ssamp + 64 * D;                                // 2 KB
        sort_columns_kernel<<<D, 64, 0, stream>>>(cen, sval, shead, ssamp, ext, out);
        cluster_triplet_bs2_kernel<<<NB / BB, 256, 0, stream>>>(x, cen, sval, shead, ssamp, ext, out);
    } else {
        float* ws = (float*)d_ws;
        hipMemsetAsync(d_out, 0, sizeof(float), stream);
        col_extremes_kernel<<<D, 256, 0, stream>>>(cen, ws);
        cluster_triplet_kernel<<<NB / BB, 256, 0, stream>>>(x, cen, ws, out);
    }
}